// Round 9
// baseline (345.180 us; speedup 1.0000x reference)
//
#include <hip/hip_runtime.h>

typedef unsigned short u16;
typedef unsigned int u32;
typedef __bf16 bf16x8 __attribute__((ext_vector_type(8)));
typedef float f32x4 __attribute__((ext_vector_type(4)));

// ---------- helpers ----------
__device__ __forceinline__ u16 f2bf(float f) {
  union { float f; u32 u; } v; v.f = f;
  u32 r = v.u + 0x7fffu + ((v.u >> 16) & 1u);   // RNE
  return (u16)(r >> 16);
}

__device__ __forceinline__ u32 pack2(float a, float b) {   // 2xbf16 (RNE via native cvt)
  union { __bf16 h[2]; u32 u; } x;
  x.h[0] = (__bf16)a; x.h[1] = (__bf16)b;
  return x.u;
}

__device__ __forceinline__ bf16x8 ldb128(const u16* p) {
  return *reinterpret_cast<const bf16x8*>(p);
}

__device__ __forceinline__ f32x4 mfma16(bf16x8 a, bf16x8 b, f32x4 c) {
  return __builtin_amdgcn_mfma_f32_16x16x32_bf16(a, b, c, 0, 0, 0);
}

template<int N> __device__ __forceinline__ void vwait() {
  asm volatile("s_waitcnt vmcnt(%0)" :: "i"(N) : "memory");
}
__device__ __forceinline__ void lgkm0_fence() {
  asm volatile("s_waitcnt lgkmcnt(0)" ::: "memory");
  __builtin_amdgcn_sched_barrier(0);
}

typedef const __attribute__((address_space(1))) u32* gas_p;
typedef __attribute__((address_space(3))) u32* las_p;
// async global->LDS, 16B per lane; lds dst is wave-uniform base + lane*16B
__device__ __forceinline__ void gld_lds16(const void* g, void* l) {
  __builtin_amdgcn_global_load_lds((gas_p)(unsigned long long)g,
                                   (las_p)(u32)(unsigned long long)l, 16, 0, 0);
}

// ---------- convert f32 -> bf16 (vectorized) ----------
__global__ __launch_bounds__(256) void cvt_f32_bf16(const float4* __restrict__ in,
                                                    uint2* __restrict__ out) {
  int i = blockIdx.x * 256 + threadIdx.x;
  float4 v = in[i];
  uint2 r;
  r.x = (u32)f2bf(v.x) | ((u32)f2bf(v.y) << 16);
  r.y = (u32)f2bf(v.z) | ((u32)f2bf(v.w) << 16);
  out[i] = r;
}

// ---------- transpose + convert: in[R][C] f32 -> out[C][R] bf16 ----------
__global__ __launch_bounds__(256) void transp_cvt(const float* __restrict__ in,
                                                  u16* __restrict__ out, int R, int C) {
  __shared__ float tile[32][33];
  int n0 = blockIdx.x * 32, k0 = blockIdx.y * 32;
  int tx = threadIdx.x, ty = threadIdx.y;   // block (32,8)
#pragma unroll
  for (int i = 0; i < 32; i += 8) tile[ty + i][tx] = in[(k0 + ty + i) * C + n0 + tx];
  __syncthreads();
#pragma unroll
  for (int i = 0; i < 32; i += 8) out[(n0 + ty + i) * R + k0 + tx] = f2bf(tile[tx][ty + i]);
}

// ---------- 8-phase GEMM (m201-style): C = A[M][K] @ Bt[N][K]^T ----------
// 512 thr = 8 waves (2M x 4N). BK=64, 2 K-tiles per 8 phases (4 phases/tile).
// Per phase: vmcnt(VM) -> s_barrier -> ds_read quadrant frags -> stage one
// half-tile of t+1 -> lgkmcnt(0)+sched_barrier -> setprio(1) MFMA setprio(0).
// Stage halves are built from per-wave quadrant row-ranges so every wave's
// phase-p fragments are certified by phase-p's vmcnt. VM = LA+LB, never 0.
// MODE 0: QKV epilogue (RoPE on Q/K, V transposed). MODE 1: plain f32 store.
template<int BM, int BN, int MODE, int LA, int LB, int VM>
__global__ __launch_bounds__(512) void gemm8p(
    const u16* __restrict__ A, const u16* __restrict__ Bt,
    int M, int N, int K,
    const float* __restrict__ cosb, const float* __restrict__ sinb,
    u16* __restrict__ Qb, u16* __restrict__ Kb, u16* __restrict__ Vt,
    float* __restrict__ outf) {
  constexpr int WTM = BM / 2, WTN = BN / 4;
  constexpr int MR = WTM / 16, NR = WTN / 16;
  constexpr int MH = MR / 2, NH = NR / 2;
  constexpr int ACH = MH * 2;             // A chunks per range-half
  constexpr int BCH = NH * 2;             // B chunks per range-half

  __shared__ u16 As[2][BM][64];
  __shared__ u16 Bs[2][BN][64];

  const int tid = threadIdx.x;
  const int wv = tid >> 6, lane = tid & 63;
  const int c = lane & 15, g = lane >> 4;
  const int swz = (c & 7) << 4;

  // XCD-aware bijective block swizzle (nwg % 8 == 0 for both instantiations)
  const int nwg = gridDim.x * gridDim.y;
  const int obid = blockIdx.y * gridDim.x + blockIdx.x;
  const int bid = (obid & 7) * (nwg >> 3) + (obid >> 3);
  const int m0 = (bid / gridDim.x) * BM;
  const int n0 = (bid % gridDim.x) * BN;

  const int wm = wv >> 2, wn = wv & 3;    // 2 x 4 wave grid

  const int lr = lane >> 3;
  const int lc8 = ((lane & 7) ^ lr) * 8;  // pre-swizzled source col (elems)

  f32x4 acc[MR][NR] = {};
  const int NT = K >> 6;

  // stage A half hm of tile t: rows {rg*WTM + hm*MH*16 + cr*8+lr : rg in 0..1}
  auto STAGE_A = [&](int buf, int t, int hm) {
#pragma unroll
    for (int li = 0; li < LA; li++) {
      const int chg = wv * LA + li;
      const int rg = chg / ACH, cr = chg % ACH;
      const int row = rg * WTM + hm * (MH * 16) + cr * 8 + lr;
      gld_lds16(A + (long)(m0 + row) * K + t * 64 + lc8, &As[buf][row - lr][0]);
    }
  };
  // stage B half hn of tile t: rows {rg*WTN + hn*NH*16 + cr*8+lr : rg in 0..3}
  auto STAGE_B = [&](int buf, int t, int hn) {
#pragma unroll
    for (int li = 0; li < LB; li++) {
      const int chg = wv * LB + li;
      const int rg = chg / BCH, cr = chg % BCH;
      const int row = rg * WTN + hn * (NH * 16) + cr * 8 + lr;
      gld_lds16(Bt + (long)(n0 + row) * K + t * 64 + lc8, &Bs[buf][row - lr][0]);
    }
  };

  bf16x8 af[MH][2], bfr[NH][2];
  auto READ_A = [&](int buf, int qm) {
#pragma unroll
    for (int i = 0; i < MH; i++)
#pragma unroll
      for (int kk = 0; kk < 2; kk++)
        af[i][kk] = ldb128(&As[buf][wm * WTM + (qm * MH + i) * 16 + c]
                               [((kk * 64 + g * 16) ^ swz) >> 1]);
  };
  auto READ_B = [&](int buf, int qn) {
#pragma unroll
    for (int j = 0; j < NH; j++)
#pragma unroll
      for (int kk = 0; kk < 2; kk++)
        bfr[j][kk] = ldb128(&Bs[buf][wn * WTN + (qn * NH + j) * 16 + c]
                                [((kk * 64 + g * 16) ^ swz) >> 1]);
  };
  auto DO_MFMA = [&](int qm, int qn) {
    __builtin_amdgcn_s_setprio(1);
#pragma unroll
    for (int kk = 0; kk < 2; kk++)
#pragma unroll
      for (int i = 0; i < MH; i++)
#pragma unroll
        for (int j = 0; j < NH; j++)
          acc[qm * MH + i][qn * NH + j] =
              mfma16(af[i][kk], bfr[j][kk], acc[qm * MH + i][qn * NH + j]);
    __builtin_amdgcn_s_setprio(0);
  };

  // prologue: tile 0, halves in order h0=A-lo, h1=B-lo, h2=A-hi, h3=B-hi
  STAGE_A(0, 0, 0); STAGE_B(0, 0, 0); STAGE_A(0, 0, 1); STAGE_B(0, 0, 1);

  for (int t = 0; t < NT; ++t) {
    const int buf = t & 1, nb = buf ^ 1;
    const bool more = (t + 1 < NT);
    // ---- phase 0: quadrant (m-lo, n-lo); needs h0,h1 ----
    vwait<VM>();
    __builtin_amdgcn_s_barrier();
    __builtin_amdgcn_sched_barrier(0);
    READ_A(buf, 0); READ_B(buf, 0);
    if (more) STAGE_A(nb, t + 1, 0);
    lgkm0_fence();
    DO_MFMA(0, 0);
    // ---- phase 1: (m-hi, n-lo); needs h2 ----
    if (more) vwait<VM>(); else vwait<LB>();
    __builtin_amdgcn_s_barrier();
    __builtin_amdgcn_sched_barrier(0);
    READ_A(buf, 1);
    if (more) STAGE_B(nb, t + 1, 0);
    lgkm0_fence();
    DO_MFMA(1, 0);
    // ---- phase 2: (m-hi, n-hi); needs h3 ----
    if (more) vwait<VM>(); else vwait<0>();
    __builtin_amdgcn_s_barrier();
    __builtin_amdgcn_sched_barrier(0);
    READ_B(buf, 1);
    if (more) STAGE_A(nb, t + 1, 1);
    lgkm0_fence();
    DO_MFMA(1, 1);
    // ---- phase 3: (m-lo, n-hi); re-reads A-lo (certified) ----
    __builtin_amdgcn_s_barrier();
    __builtin_amdgcn_sched_barrier(0);
    READ_A(buf, 0);
    if (more) STAGE_B(nb, t + 1, 1);
    lgkm0_fence();
    DO_MFMA(0, 1);
  }

  // ---------- epilogue ----------
  // Q absorbs 1/sqrt(hd) * log2(e) so attention can use exp2 directly.
  const float q_scale = 0.12751743f;
#pragma unroll
  for (int i = 0; i < MR; i++) {
#pragma unroll
    for (int j = 0; j < NR; j++) {
      const int ncol = n0 + wn * WTN + j * 16 + c;
      if (MODE == 1) {
#pragma unroll
        for (int r = 0; r < 4; r++) {
          const int m = m0 + wm * WTM + i * 16 + g * 4 + r;
          outf[(long)m * N + ncol] = acc[i][j][r];
        }
        continue;
      }
      if (ncol < 2560) {                // Q or K: RoPE
#pragma unroll
        for (int r = 0; r < 4; r++) {
          const int m = m0 + wm * WTM + i * 16 + g * 4 + r;
          const int s = m & 2047;
          const int d = ncol & 127;
          float val = acc[i][j][r];
          float ct = cosb[s * 128 + d], st = sinb[s * 128 + d];
          float pr = __shfl_xor(val, 1, 64);
          float rot = (ncol & 1) ? pr : -pr;
          float rp = val * ct + rot * st;
          if (ncol < 2048) Qb[m * 2048 + ncol] = f2bf(rp * q_scale);
          else             Kb[m * 512 + (ncol - 2048)] = f2bf(rp);
        }
      } else {                          // V: store transposed Vt[bkvh*128+d][s]
        const int m_base = m0 + wm * WTM + i * 16 + g * 4;
        const int bb = m_base >> 11;
        const int srow = m_base & 2047;
        uint2 pv;
        pv.x = pack2(acc[i][j][0], acc[i][j][1]);
        pv.y = pack2(acc[i][j][2], acc[i][j][3]);
        *(uint2*)&Vt[(bb * 512 + (ncol - 2560)) * 2048 + srow] = pv;
      }
    }
  }
}

// ---------- flash attention v3: 2 q-sets/wave, double-buffered K/V, exp2 ----------
// Block: 4 waves x 32 q-rows = 128 q. KV tile 64. K/V XOR-swizzled via source.
__global__ __launch_bounds__(256, 2) void attn_fwd(
    const u16* __restrict__ Qb, const u16* __restrict__ Kb,
    const u16* __restrict__ Vt, u16* __restrict__ attnb) {
  __shared__ u16 Ks[2][64 * 128];       // [key][d] swizzled, double-buffered
  __shared__ u16 Vs[2][128 * 64];       // [d][key] swizzled
  __shared__ u16 Pl[4][2][16 * 64];     // per-wave, per-set P [q][k] swizzled
  const int tid = threadIdx.x;
  const int wv = tid >> 6, lane = tid & 63;
  const int c = lane & 15, g = lane >> 4;
  const int qt = 15 - (int)blockIdx.x;  // heavy blocks first
  const int h = blockIdx.y, b = blockIdx.z;
  const int kvh = h >> 2;
  const int qbase = qt * 128 + wv * 32; // +set*16+c
  const int swz = (c & 7) << 4;

  bf16x8 qf0[4], qf1[4];
  {
    const u16* qp0 = Qb + ((b << 11) + qbase + c) * 2048 + h * 128 + g * 8;
#pragma unroll
    for (int dc = 0; dc < 4; dc++) qf0[dc] = ldb128(qp0 + dc * 32);
    const u16* qp1 = qp0 + 16 * 2048;
#pragma unroll
    for (int dc = 0; dc < 4; dc++) qf1[dc] = ldb128(qp1 + dc * 32);
  }

  f32x4 oacc0[8] = {}, oacc1[8] = {};
  float m0r = -1e30f, l0r = 0.f, m1r = -1e30f, l1r = 0.f;

  const int krow = wv * 16 + g;
  const int vrow = wv * 32 + (lane >> 3);
  const u16* Kg = Kb + kvh * 128;
  const u16* Vg = Vt + (b * 512 + kvh * 128) * 2048;
  const int NKV = 2 * qt + 2;

  auto STAGE = [&](int buf, int t) {
    const int k0 = t * 64;
#pragma unroll
    for (int i = 0; i < 4; i++) {
      const int r = krow + i * 4;
      gld_lds16(Kg + ((long)(b * 2048 + k0 + r)) * 512 + ((c ^ (r & 7)) * 8),
                &Ks[buf][(wv * 4 + i) * 512]);
    }
#pragma unroll
    for (int i = 0; i < 4; i++) {
      const int r = vrow + i * 8;
      gld_lds16(Vg + (long)r * 2048 + k0 + (((lane & 7) ^ (r & 7)) * 8),
                &Vs[buf][(wv * 4 + i) * 512]);
    }
  };

  STAGE(0, 0);
  for (int kt = 0; kt < NKV; kt++) {
    const int buf = kt & 1;
    const int k0 = kt * 64;
    if (kt + 1 < NKV) {
      STAGE(buf ^ 1, kt + 1);
      asm volatile("s_waitcnt vmcnt(8)" ::: "memory");
    } else {
      asm volatile("s_waitcnt vmcnt(0)" ::: "memory");
    }
    __builtin_amdgcn_s_barrier();
    __builtin_amdgcn_sched_barrier(0);

    f32x4 t0[4] = {}, t1[4] = {};
    __builtin_amdgcn_s_setprio(1);
#pragma unroll
    for (int kf = 0; kf < 4; kf++) {
#pragma unroll
      for (int dc = 0; dc < 4; dc++) {
        const bf16x8 kfr =
            ldb128(&Ks[buf][(kf * 16 + c) * 128 + (((dc * 64 + g * 16) ^ swz) >> 1)]);
        t0[kf] = mfma16(kfr, qf0[dc], t0[kf]);
        t1[kf] = mfma16(kfr, qf1[dc], t1[kf]);
      }
    }
    __builtin_amdgcn_s_setprio(0);
    if (kt >= NKV - 2) {                 // diagonal region: causal mask
      const int q0 = qbase + c, q1 = q0 + 16;
#pragma unroll
      for (int kf = 0; kf < 4; kf++)
#pragma unroll
        for (int r = 0; r < 4; r++) {
          const int key = k0 + kf * 16 + g * 4 + r;
          if (key > q0) t0[kf][r] = -1e30f;
          if (key > q1) t1[kf][r] = -1e30f;
        }
    }
#pragma unroll
    for (int s = 0; s < 2; s++) {
      f32x4* t = s ? t1 : t0;
      float& mr = s ? m1r : m0r;
      float& lr_ = s ? l1r : l0r;
      f32x4* oa = s ? oacc1 : oacc0;
      float pmax = -1e30f;
#pragma unroll
      for (int kf = 0; kf < 4; kf++)
#pragma unroll
        for (int r = 0; r < 4; r++) pmax = fmaxf(pmax, t[kf][r]);
      pmax = fmaxf(pmax, __shfl_xor(pmax, 16, 64));
      pmax = fmaxf(pmax, __shfl_xor(pmax, 32, 64));
      if (__any(pmax - mr > 8.f)) {
        const float mnew = fmaxf(mr, pmax);
        const float scale = __builtin_amdgcn_exp2f(mr - mnew);
        lr_ *= scale;
#pragma unroll
        for (int df = 0; df < 8; df++) oa[df] *= scale;
        mr = mnew;
      }
      float psum = 0.f;
#pragma unroll
      for (int kf = 0; kf < 4; kf++) {
        float p0 = __builtin_amdgcn_exp2f(t[kf][0] - mr);
        float p1 = __builtin_amdgcn_exp2f(t[kf][1] - mr);
        float p2 = __builtin_amdgcn_exp2f(t[kf][2] - mr);
        float p3 = __builtin_amdgcn_exp2f(t[kf][3] - mr);
        psum += (p0 + p1) + (p2 + p3);
        u32* pw = (u32*)&Pl[wv][s][c * 64 + (((kf * 32 + g * 8) ^ swz) >> 1)];
        pw[0] = pack2(p0, p1);
        pw[1] = pack2(p2, p3);
      }
      psum += __shfl_xor(psum, 16, 64);
      psum += __shfl_xor(psum, 32, 64);
      lr_ += psum;
    }

    const bf16x8 pa0 = ldb128(&Pl[wv][0][c * 64 + (((g * 16) ^ swz) >> 1)]);
    const bf16x8 pa1 = ldb128(&Pl[wv][0][c * 64 + (((64 + g * 16) ^ swz) >> 1)]);
    const bf16x8 pb0 = ldb128(&Pl[wv][1][c * 64 + (((g * 16) ^ swz) >> 1)]);
    const bf16x8 pb1 = ldb128(&Pl[wv][1][c * 64 + (((64 + g * 16) ^ swz) >> 1)]);
    __builtin_amdgcn_s_setprio(1);
#pragma unroll
    for (int df = 0; df < 8; df++) {
      const int vb = (df * 16 + c) * 64;
      const bf16x8 v0 = ldb128(&Vs[buf][vb + (((g * 16) ^ swz) >> 1)]);
      const bf16x8 v1 = ldb128(&Vs[buf][vb + (((64 + g * 16) ^ swz) >> 1)]);
      oacc0[df] = mfma16(v0, pa0, oacc0[df]);
      oacc0[df] = mfma16(v1, pa1, oacc0[df]);
      oacc1[df] = mfma16(v0, pb0, oacc1[df]);
      oacc1[df] = mfma16(v1, pb1, oacc1[df]);
    }
    __builtin_amdgcn_s_setprio(0);
    __builtin_amdgcn_sched_barrier(0);
    asm volatile("" ::: "memory");
    __builtin_amdgcn_s_barrier();
  }

  const float ri0 = 1.f / l0r, ri1 = 1.f / l1r;
  const long ob0 = ((long)(b << 11) + qbase + c) * 2048 + h * 128 + g * 4;
#pragma unroll
  for (int df = 0; df < 8; df++) {
    uint2 o0, o1;
    o0.x = pack2(oacc0[df][0] * ri0, oacc0[df][1] * ri0);
    o0.y = pack2(oacc0[df][2] * ri0, oacc0[df][3] * ri0);
    o1.x = pack2(oacc1[df][0] * ri1, oacc1[df][1] * ri1);
    o1.y = pack2(oacc1[df][2] * ri1, oacc1[df][3] * ri1);
    *(uint2*)&attnb[ob0 + df * 16] = o0;
    *(uint2*)&attnb[ob0 + 16 * 2048 + df * 16] = o1;
  }
}

// ---------- launch ----------
extern "C" void kernel_launch(void* const* d_in, const int* in_sizes, int n_in,
                              void* d_out, int out_size, void* d_ws, size_t ws_size,
                              hipStream_t stream) {
  const float* X    = (const float*)d_in[0];  // (2,2048,2048)
  const float* cosb = (const float*)d_in[1];  // (2048,128)
  const float* sinb = (const float*)d_in[2];
  const float* Wq   = (const float*)d_in[3];  // (2048,2048)
  const float* Wk   = (const float*)d_in[4];  // (2048,512)
  const float* Wv   = (const float*)d_in[5];
  const float* Wo   = (const float*)d_in[6];  // (2048,2048)

  char* ws = (char*)d_ws;
  u16* Xb    = (u16*)(ws);                       // 4096x2048 bf16 : 16 MB
  u16* Wt    = (u16*)(ws + 16777216);            // 3072x2048 bf16 : 12 MB (Wq^T|Wk^T|Wv^T)
  u16* Wot   = (u16*)(ws + 29360128);            // 2048x2048 bf16 : 8 MB
  u16* Qb    = (u16*)(ws + 37748736);            // 4096x2048 bf16 : 16 MB
  u16* Kb    = (u16*)(ws + 54525952);            // 4096x512  bf16 : 4 MB
  u16* Vt    = (u16*)(ws + 58720256);            // 1024x2048 bf16 : 4 MB
  u16* attnb = Xb;                               // alias: Xb dead after QKV GEMM

  // 1) convert hidden to bf16
  cvt_f32_bf16<<<dim3(8192), dim3(256), 0, stream>>>((const float4*)X, (uint2*)Xb);
  // 2) transpose+convert weights -> [N][K] bf16
  transp_cvt<<<dim3(64, 64), dim3(32, 8), 0, stream>>>(Wq, Wt, 2048, 2048);
  transp_cvt<<<dim3(16, 64), dim3(32, 8), 0, stream>>>(Wk, Wt + 2048 * 2048, 2048, 512);
  transp_cvt<<<dim3(16, 64), dim3(32, 8), 0, stream>>>(Wv, Wt + 2560 * 2048, 2048, 512);
  transp_cvt<<<dim3(64, 64), dim3(32, 8), 0, stream>>>(Wo, Wot, 2048, 2048);
  // 3) fused QKV GEMM + RoPE epilogue (256x256 8-phase, grid 12x16=192)
  gemm8p<256, 256, 0, 2, 2, 4><<<dim3(12, 16), dim3(512), 0, stream>>>(
      Xb, Wt, 4096, 3072, 2048, cosb, sinb, Qb, Kb, Vt, nullptr);
  // 4) causal GQA flash attention (128 q/block, 512 blocks, 2 blocks/CU)
  attn_fwd<<<dim3(16, 16, 2), dim3(256), 0, stream>>>(Qb, Kb, Vt, attnb);
  // 5) output GEMM -> f32 d_out (128x256 8-phase, grid 8x32=256)
  gemm8p<128, 256, 1, 1, 2, 3><<<dim3(8, 32), dim3(512), 0, stream>>>(
      attnb, Wot, 4096, 2048, 2048, nullptr, nullptr, nullptr, nullptr, nullptr,
      (float*)d_out);
}